// Round 13
// baseline (59.283 us; speedup 1.0000x reference)
//
#include <hip/hip_runtime.h>

// ODEDriftIntegrator: integrate x' = drift(x,u) over [0,0.01] per point
// (midpoint rule, validated R10: truncation ~2e-5 vs dopri5x4), diffusion
// kick, then yhat[b] = sum_s W[b,s] x_end[b,s].
//
// R13 = R12 math untouched; occupancy/amortization fix. R12 counters:
// VALUBusy 34, MfmaUtil 8, HBM 1.2%, Occupancy 27% -- latency-bound, grid
// 2048 x (256,3) left only ~2.7 blocks/CU resident with dispatch rounds and
// 1 job/wave (setup unamortized). Now: grid 1024 = 256 CU x 4 blocks with
// __launch_bounds__(256,4) (VGPR cap 128 >= measured 84 demand -> no spill):
// whole grid co-resident, zero tail, 2 jobs/wave halves setup overhead.
//
// RHS pipeline unchanged: job = 16 outputs, lane carries all 5 sigma-points
// (lane-local s-reduction, zero atomics); mfma_f32_16x16x32_f16 layer2
// (W2^T @ H1^T, point==lane&15); 4-op packed-f16 half-sigmoid tanh (VOP3P
// clamp); affine fold via W2-colsum C-init and 2*W3 epilogue.

typedef __attribute__((ext_vector_type(2))) __fp16 h2;
typedef __attribute__((ext_vector_type(8))) __fp16 h8;
typedef __attribute__((ext_vector_type(4))) float f32x4;

#define NOUT   131072
#define NJOBS  (NOUT / 16)           // 8192 jobs of 16 outputs x 5 chains

// packed-half constants (both halves identical) -- halved validated quartic
#define C0H 0x3B913B91u  //  0.9458   (= 1.8916/2)
#define C1H 0xB996B996u  // -0.69824  (= -1.3965/2)
#define HALFC 0x38003800u//  0.5

__device__ __forceinline__ unsigned u_of(h2 x) { return __builtin_bit_cast(unsigned, x); }
__device__ __forceinline__ unsigned pkrtz_u(float a, float b) {
  return u_of(__builtin_amdgcn_cvt_pkrtz(a, b));
}
__device__ __forceinline__ unsigned pk_fma_vvv(unsigned a, unsigned b, unsigned c) {
  unsigned d; asm("v_pk_fma_f16 %0, %1, %2, %3" : "=v"(d) : "v"(a), "v"(b), "v"(c)); return d;
}
__device__ __forceinline__ unsigned pk_fma_vvs(unsigned a, unsigned b, unsigned cs) {
  unsigned d; asm("v_pk_fma_f16 %0, %1, %2, %3" : "=v"(d) : "v"(a), "v"(b), "s"(cs)); return d;
}
__device__ __forceinline__ unsigned pk_fma_clamp_vvs(unsigned a, unsigned b, unsigned cs) {
  unsigned d; asm("v_pk_fma_f16 %0, %1, %2, %3 clamp" : "=v"(d) : "v"(a), "v"(b), "s"(cs)); return d;
}
__device__ __forceinline__ unsigned pk_mul_vv(unsigned a, unsigned b) {
  unsigned d; asm("v_pk_mul_f16 %0, %1, %2" : "=v"(d) : "v"(a), "v"(b)); return d;
}
// 4-op half-sigmoid: q = clamp01(0.5 + s*(c0h + c1h*w + c2h*w^2)), w=s*s.
__device__ __forceinline__ unsigned tanh4(unsigned s, unsigned c2v) {
  unsigned w = pk_mul_vv(s, s);
  unsigned p = pk_fma_vvs(c2v, w, C1H);
  p = pk_fma_vvs(p, w, C0H);
  return pk_fma_clamp_vvs(s, p, HALFC);
}

union HU { unsigned u[4]; h8 v; };

__global__ __launch_bounds__(256, 4) void ode_mfma_kernel(
    const float* __restrict__ sigmap,  // [NPTS,3]
    const float* __restrict__ Wpp,     // [NPTS]
    const float* __restrict__ W1p,     // [2,64]
    const float* __restrict__ b1p,     // [64]
    const float* __restrict__ W2p,     // [64,64]
    const float* __restrict__ b2p,     // [64]
    const float* __restrict__ W3p,     // [64,1]
    const float* __restrict__ b3p,     // [1]
    float* __restrict__ outp)          // [131072]
{
  const int lane = threadIdx.x & 63;
  const int col  = lane & 15;   // output slot within job (B-col == D-col)
  const int g    = lane >> 4;   // lane group (k-group / D-row group)
  const int wid  = blockIdx.x * (blockDim.x >> 6) + (threadIdx.x >> 6);
  const int nw   = gridDim.x * (blockDim.x >> 6);

  // pinned VGPR for c2h = 0.20898 packed
  unsigned c2v; asm("v_mov_b32 %0, 0x32B032B0" : "=v"(c2v));

  // colsum[j] = sum_k W2[k][j], once per block (256B LDS)
  __shared__ float colsum[64];
  if (threadIdx.x < 64) {
    float s = 0.0f;
    for (int k = 0; k < 64; ++k) s += W2p[k * 64 + threadIdx.x];
    colsum[threadIdx.x] = s;
  }
  __syncthreads();

  // ---- persistent per-lane constants ----
  // layer1 packed pair ee: ee<4 -> j0=8g+2ee (k-frag 0); ee>=4 -> 32+8g+2(ee-4).
  unsigned w10u[8], w11u[8], b01u[8];
#pragma unroll
  for (int ee = 0; ee < 8; ++ee) {
    int j0 = (ee < 4) ? (8 * g + 2 * ee) : (32 + 8 * g + 2 * (ee - 4));
    w10u[ee] = pkrtz_u(0.5f * W1p[j0],      0.5f * W1p[j0 + 1]);
    w11u[ee] = pkrtz_u(0.5f * W1p[64 + j0], 0.5f * W1p[64 + j0 + 1]);
    b01u[ee] = pkrtz_u(0.5f * b1p[j0],      0.5f * b1p[j0 + 1]);
  }
  // A-frags = W2^T RAW (sigmoid-fold cancels the 0.5x2).
  HU afr[4][2];
#pragma unroll
  for (int t = 0; t < 4; ++t)
#pragma unroll
    for (int kt = 0; kt < 2; ++kt)
#pragma unroll
      for (int ee = 0; ee < 4; ++ee) {
        int k0 = kt * 32 + 8 * g + 2 * ee;
        afr[t][kt].u[ee] = pkrtz_u(W2p[(k0)     * 64 + 16 * t + col],
                                   W2p[(k0 + 1) * 64 + 16 * t + col]);
      }
  // D-side: lane reg r of tile t -> j=16t+4g+r. C-init = 0.5*(b2[j]-colsum[j]).
  f32x4 cinit[4];
  unsigned w3u[8];   // 2*W3 packed (sigmoid fold)
#pragma unroll
  for (int t = 0; t < 4; ++t) {
    int jb = 16 * t + 4 * g;
#pragma unroll
    for (int r = 0; r < 4; ++r) cinit[t][r] = 0.5f * (b2p[jb + r] - colsum[jb + r]);
    w3u[2 * t]     = pkrtz_u(2.0f * W3p[jb],     2.0f * W3p[jb + 1]);
    w3u[2 * t + 1] = pkrtz_u(2.0f * W3p[jb + 2], 2.0f * W3p[jb + 3]);
  }
  float sw3 = 0.0f;
  for (int k = 0; k < 64; ++k) sw3 += W3p[k];
  const float b3v = b3p[0] - sw3;   // y = 2*W3^T q2 + (b3 - sum W3)

#pragma unroll 1
  for (int job = wid; job < NJOBS; job += nw) {
    const int pbase = job * 80 + 5 * col;   // point p = pbase + s, s=0..4

    float x[5];
    unsigned uh[5];
#pragma unroll
    for (int s = 0; s < 5; ++s) {
      const int p = pbase + s;
      x[s]  = sigmap[3 * p + 0];
      float us = sigmap[3 * p + 1];
      uh[s] = pkrtz_u(us, us);
    }

    // 5-chain RHS: s-outer / tile-inner. o[s] = drift(xi[s], u[s]).
    auto rhs5 = [&](const float* xi, float* o) {
#pragma unroll
      for (int s = 0; s < 5; ++s) {
        unsigned xh = pkrtz_u(xi[s], xi[s]);
        HU b0, b1;
#pragma unroll
        for (int ee = 0; ee < 4; ++ee) {
          unsigned cv0 = pk_fma_vvv(uh[s], w11u[ee],     b01u[ee]);
          unsigned cv1 = pk_fma_vvv(uh[s], w11u[ee + 4], b01u[ee + 4]);
          b0.u[ee] = tanh4(pk_fma_vvv(xh, w10u[ee],     cv0), c2v);
          b1.u[ee] = tanh4(pk_fma_vvv(xh, w10u[ee + 4], cv1), c2v);
        }
        unsigned ph = 0;
#pragma unroll
        for (int t = 0; t < 4; ++t) {
          f32x4 a = cinit[t];
          a = __builtin_amdgcn_mfma_f32_16x16x32_f16(afr[t][0].v, b0.v, a, 0, 0, 0);
          a = __builtin_amdgcn_mfma_f32_16x16x32_f16(afr[t][1].v, b1.v, a, 0, 0, 0);
          unsigned t0 = tanh4(pkrtz_u(a[0], a[1]), c2v);
          unsigned t1 = tanh4(pkrtz_u(a[2], a[3]), c2v);
          ph = pk_fma_vvv(t0, w3u[2 * t],     ph);
          ph = pk_fma_vvv(t1, w3u[2 * t + 1], ph);
        }
        h2 hh = __builtin_bit_cast(h2, ph);
        float sv = (float)hh[0] + (float)hh[1];
        sv += __shfl_xor(sv, 16, 64);
        sv += __shfl_xor(sv, 32, 64);
        o[s] = sv + b3v;
      }
    };

    // midpoint: x_end = x0 + DT * f(x0 + DT/2 * f(x0)); then diffusion kick.
    float k1[5], k2[5];
    rhs5(x, k1);
#pragma unroll
    for (int s = 0; s < 5; ++s) k1[s] = fmaf(0.005f, k1[s], x[s]);  // xm in-place
    rhs5(k1, k2);

    // final combine: wd/wq loaded here (L2-hit) instead of held in regs.
    float y = 0.0f;
#pragma unroll
    for (int s = 0; s < 5; ++s) {
      const int p = pbase + s;
      float xe = fmaf(0.01f, k2[s], x[s]);
      xe = fmaf(0.01f, sigmap[3 * p + 2], xe);  // sqrt(2*0.5*sigma^2*dt)=0.01
      y = fmaf(Wpp[p], xe, y);
    }

    if (lane < 16) outp[job * 16 + col] = y;   // plain store, no atomics
  }
}

extern "C" void kernel_launch(void* const* d_in, const int* in_sizes, int n_in,
                              void* d_out, int out_size, void* d_ws, size_t ws_size,
                              hipStream_t stream) {
  const float* sigmap = (const float*)d_in[0];
  const float* Wpp    = (const float*)d_in[1];
  const float* W1p    = (const float*)d_in[2];
  const float* b1p    = (const float*)d_in[3];
  const float* W2p    = (const float*)d_in[4];
  const float* b2p    = (const float*)d_in[5];
  const float* W3p    = (const float*)d_in[6];
  const float* b3p    = (const float*)d_in[7];
  float* outp = (float*)d_out;

  // whole grid co-resident: 1024 blocks = 256 CU x 4; 2 jobs per wave.
  ode_mfma_kernel<<<1024, 256, 0, stream>>>(sigmap, Wpp, W1p, b1p, W2p, b2p,
                                            W3p, b3p, outp);
  (void)d_ws; (void)ws_size; (void)n_in; (void)in_sizes;
}

// Round 14
// 30.958 us; speedup vs baseline: 1.9150x; 1.9150x over previous
//
#include <hip/hip_runtime.h>

// ODEDriftIntegrator: integrate x' = drift(x,u) over [0,0.01] per point
// (midpoint rule, validated R10: truncation ~2e-5 vs dopri5x4), diffusion
// kick, then yhat[b] = sum_s W[b,s] x_end[b,s].
//
// R14 = R12 math + register budget, R13 grid idea, decoupled:
//   - __launch_bounds__(256, 3): empirically cap ~85 VGPR (R12: VGPR=84, no
//     spill). (256,4) caps at 64 on this toolchain -> R13's 127MB respill.
//   - grid 1024 = 4 blocks/CU <= ~6 resident capacity @84 VGPR: whole grid
//     co-resident, no dispatch rounds, no tail; 4096 waves x exactly 2
//     jobs/wave (setup amortized 2x vs R12's 1 job/wave + 2 rounds).
//
// RHS pipeline unchanged: job = 16 outputs, lane carries all 5 sigma-points
// (lane-local s-reduction, zero atomics); mfma_f32_16x16x32_f16 layer2
// (W2^T @ H1^T, point==lane&15); 4-op packed-f16 half-sigmoid tanh (VOP3P
// clamp); affine fold via W2-colsum C-init and 2*W3 epilogue.

typedef __attribute__((ext_vector_type(2))) __fp16 h2;
typedef __attribute__((ext_vector_type(8))) __fp16 h8;
typedef __attribute__((ext_vector_type(4))) float f32x4;

#define NOUT   131072
#define NJOBS  (NOUT / 16)           // 8192 jobs of 16 outputs x 5 chains

// packed-half constants (both halves identical) -- halved validated quartic
#define C0H 0x3B913B91u  //  0.9458   (= 1.8916/2)
#define C1H 0xB996B996u  // -0.69824  (= -1.3965/2)
#define HALFC 0x38003800u//  0.5

__device__ __forceinline__ unsigned u_of(h2 x) { return __builtin_bit_cast(unsigned, x); }
__device__ __forceinline__ unsigned pkrtz_u(float a, float b) {
  return u_of(__builtin_amdgcn_cvt_pkrtz(a, b));
}
__device__ __forceinline__ unsigned pk_fma_vvv(unsigned a, unsigned b, unsigned c) {
  unsigned d; asm("v_pk_fma_f16 %0, %1, %2, %3" : "=v"(d) : "v"(a), "v"(b), "v"(c)); return d;
}
__device__ __forceinline__ unsigned pk_fma_vvs(unsigned a, unsigned b, unsigned cs) {
  unsigned d; asm("v_pk_fma_f16 %0, %1, %2, %3" : "=v"(d) : "v"(a), "v"(b), "s"(cs)); return d;
}
__device__ __forceinline__ unsigned pk_fma_clamp_vvs(unsigned a, unsigned b, unsigned cs) {
  unsigned d; asm("v_pk_fma_f16 %0, %1, %2, %3 clamp" : "=v"(d) : "v"(a), "v"(b), "s"(cs)); return d;
}
__device__ __forceinline__ unsigned pk_mul_vv(unsigned a, unsigned b) {
  unsigned d; asm("v_pk_mul_f16 %0, %1, %2" : "=v"(d) : "v"(a), "v"(b)); return d;
}
// 4-op half-sigmoid: q = clamp01(0.5 + s*(c0h + c1h*w + c2h*w^2)), w=s*s.
__device__ __forceinline__ unsigned tanh4(unsigned s, unsigned c2v) {
  unsigned w = pk_mul_vv(s, s);
  unsigned p = pk_fma_vvs(c2v, w, C1H);
  p = pk_fma_vvs(p, w, C0H);
  return pk_fma_clamp_vvs(s, p, HALFC);
}

union HU { unsigned u[4]; h8 v; };

__global__ __launch_bounds__(256, 3) void ode_mfma_kernel(
    const float* __restrict__ sigmap,  // [NPTS,3]
    const float* __restrict__ Wpp,     // [NPTS]
    const float* __restrict__ W1p,     // [2,64]
    const float* __restrict__ b1p,     // [64]
    const float* __restrict__ W2p,     // [64,64]
    const float* __restrict__ b2p,     // [64]
    const float* __restrict__ W3p,     // [64,1]
    const float* __restrict__ b3p,     // [1]
    float* __restrict__ outp)          // [131072]
{
  const int lane = threadIdx.x & 63;
  const int col  = lane & 15;   // output slot within job (B-col == D-col)
  const int g    = lane >> 4;   // lane group (k-group / D-row group)
  const int wid  = blockIdx.x * (blockDim.x >> 6) + (threadIdx.x >> 6);
  const int nw   = gridDim.x * (blockDim.x >> 6);

  // pinned VGPR for c2h = 0.20898 packed
  unsigned c2v; asm("v_mov_b32 %0, 0x32B032B0" : "=v"(c2v));

  // colsum[j] = sum_k W2[k][j], once per block (256B LDS)
  __shared__ float colsum[64];
  if (threadIdx.x < 64) {
    float s = 0.0f;
    for (int k = 0; k < 64; ++k) s += W2p[k * 64 + threadIdx.x];
    colsum[threadIdx.x] = s;
  }
  __syncthreads();

  // ---- persistent per-lane constants ----
  // layer1 packed pair ee: ee<4 -> j0=8g+2ee (k-frag 0); ee>=4 -> 32+8g+2(ee-4).
  unsigned w10u[8], w11u[8], b01u[8];
#pragma unroll
  for (int ee = 0; ee < 8; ++ee) {
    int j0 = (ee < 4) ? (8 * g + 2 * ee) : (32 + 8 * g + 2 * (ee - 4));
    w10u[ee] = pkrtz_u(0.5f * W1p[j0],      0.5f * W1p[j0 + 1]);
    w11u[ee] = pkrtz_u(0.5f * W1p[64 + j0], 0.5f * W1p[64 + j0 + 1]);
    b01u[ee] = pkrtz_u(0.5f * b1p[j0],      0.5f * b1p[j0 + 1]);
  }
  // A-frags = W2^T RAW (sigmoid-fold cancels the 0.5x2).
  HU afr[4][2];
#pragma unroll
  for (int t = 0; t < 4; ++t)
#pragma unroll
    for (int kt = 0; kt < 2; ++kt)
#pragma unroll
      for (int ee = 0; ee < 4; ++ee) {
        int k0 = kt * 32 + 8 * g + 2 * ee;
        afr[t][kt].u[ee] = pkrtz_u(W2p[(k0)     * 64 + 16 * t + col],
                                   W2p[(k0 + 1) * 64 + 16 * t + col]);
      }
  // D-side: lane reg r of tile t -> j=16t+4g+r. C-init = 0.5*(b2[j]-colsum[j]).
  f32x4 cinit[4];
  unsigned w3u[8];   // 2*W3 packed (sigmoid fold)
#pragma unroll
  for (int t = 0; t < 4; ++t) {
    int jb = 16 * t + 4 * g;
#pragma unroll
    for (int r = 0; r < 4; ++r) cinit[t][r] = 0.5f * (b2p[jb + r] - colsum[jb + r]);
    w3u[2 * t]     = pkrtz_u(2.0f * W3p[jb],     2.0f * W3p[jb + 1]);
    w3u[2 * t + 1] = pkrtz_u(2.0f * W3p[jb + 2], 2.0f * W3p[jb + 3]);
  }
  float sw3 = 0.0f;
  for (int k = 0; k < 64; ++k) sw3 += W3p[k];
  const float b3v = b3p[0] - sw3;   // y = 2*W3^T q2 + (b3 - sum W3)

#pragma unroll 1
  for (int job = wid; job < NJOBS; job += nw) {
    const int pbase = job * 80 + 5 * col;   // point p = pbase + s, s=0..4

    float x[5];
    unsigned uh[5];
#pragma unroll
    for (int s = 0; s < 5; ++s) {
      const int p = pbase + s;
      x[s]  = sigmap[3 * p + 0];
      float us = sigmap[3 * p + 1];
      uh[s] = pkrtz_u(us, us);
    }

    // 5-chain RHS: s-outer / tile-inner. o[s] = drift(xi[s], u[s]).
    auto rhs5 = [&](const float* xi, float* o) {
#pragma unroll
      for (int s = 0; s < 5; ++s) {
        unsigned xh = pkrtz_u(xi[s], xi[s]);
        HU b0, b1;
#pragma unroll
        for (int ee = 0; ee < 4; ++ee) {
          unsigned cv0 = pk_fma_vvv(uh[s], w11u[ee],     b01u[ee]);
          unsigned cv1 = pk_fma_vvv(uh[s], w11u[ee + 4], b01u[ee + 4]);
          b0.u[ee] = tanh4(pk_fma_vvv(xh, w10u[ee],     cv0), c2v);
          b1.u[ee] = tanh4(pk_fma_vvv(xh, w10u[ee + 4], cv1), c2v);
        }
        unsigned ph = 0;
#pragma unroll
        for (int t = 0; t < 4; ++t) {
          f32x4 a = cinit[t];
          a = __builtin_amdgcn_mfma_f32_16x16x32_f16(afr[t][0].v, b0.v, a, 0, 0, 0);
          a = __builtin_amdgcn_mfma_f32_16x16x32_f16(afr[t][1].v, b1.v, a, 0, 0, 0);
          unsigned t0 = tanh4(pkrtz_u(a[0], a[1]), c2v);
          unsigned t1 = tanh4(pkrtz_u(a[2], a[3]), c2v);
          ph = pk_fma_vvv(t0, w3u[2 * t],     ph);
          ph = pk_fma_vvv(t1, w3u[2 * t + 1], ph);
        }
        h2 hh = __builtin_bit_cast(h2, ph);
        float sv = (float)hh[0] + (float)hh[1];
        sv += __shfl_xor(sv, 16, 64);
        sv += __shfl_xor(sv, 32, 64);
        o[s] = sv + b3v;
      }
    };

    // midpoint: x_end = x0 + DT * f(x0 + DT/2 * f(x0)); then diffusion kick.
    float k1[5], k2[5];
    rhs5(x, k1);
#pragma unroll
    for (int s = 0; s < 5; ++s) k1[s] = fmaf(0.005f, k1[s], x[s]);  // xm in-place
    rhs5(k1, k2);

    // final combine: wd/wq loaded here (L2-hit) instead of held in regs.
    float y = 0.0f;
#pragma unroll
    for (int s = 0; s < 5; ++s) {
      const int p = pbase + s;
      float xe = fmaf(0.01f, k2[s], x[s]);
      xe = fmaf(0.01f, sigmap[3 * p + 2], xe);  // sqrt(2*0.5*sigma^2*dt)=0.01
      y = fmaf(Wpp[p], xe, y);
    }

    if (lane < 16) outp[job * 16 + col] = y;   // plain store, no atomics
  }
}

extern "C" void kernel_launch(void* const* d_in, const int* in_sizes, int n_in,
                              void* d_out, int out_size, void* d_ws, size_t ws_size,
                              hipStream_t stream) {
  const float* sigmap = (const float*)d_in[0];
  const float* Wpp    = (const float*)d_in[1];
  const float* W1p    = (const float*)d_in[2];
  const float* b1p    = (const float*)d_in[3];
  const float* W2p    = (const float*)d_in[4];
  const float* b2p    = (const float*)d_in[5];
  const float* W3p    = (const float*)d_in[6];
  const float* b3p    = (const float*)d_in[7];
  float* outp = (float*)d_out;

  // 1024 blocks = 4/CU <= ~6 resident capacity @ 84 VGPR: fully co-resident,
  // 4096 waves x exactly 2 jobs each.
  ode_mfma_kernel<<<1024, 256, 0, stream>>>(sigmap, Wpp, W1p, b1p, W2p, b2p,
                                            W3p, b3p, outp);
  (void)d_ws; (void)ws_size; (void)n_in; (void)in_sizes;
}

// Round 15
// 28.705 us; speedup vs baseline: 2.0653x; 1.0785x over previous
//
#include <hip/hip_runtime.h>

// ODEDriftIntegrator: integrate x' = drift(x,u) over [0,0.01] per point
// (midpoint rule, validated R10), diffusion kick, yhat[b] = sum_s W x_end.
//
// R15 = R14 + R8's shuffle-free W3-MFMA epilogue (math validated in R8,
// absmax 0.0078125; R8 only failed on registers under its 2-batch layout).
// R14 counters: latency-bound (VALUBusy 30%, Occ 24%, issue floor ~7us vs
// 31us) with 2 serial ds_bpermute shuffles per chain-rhs on the critical
// path. Now: layer2 A-side uses permutation j_of(t,i) = 32(t>>1) + 8(i>>2)
// + 4(t&1) + (i&3) so each lane's 16 tanh'd layer2 outputs are exactly the
// B-fragment k-set (k = kt*32+8g+e, e=4(t&1)+r) of a W3-MFMA with
// A2 = 2*W3[k] broadcast (rows identical), C-init = b3 - sum(W3):
// D = y[col] replicated in all lanes, f32 -- zero shuffles, zero unpack.
// Per chain-rhs: -8 pk_fma -2 cvt -3 add -2 shfl, +2 MFMA (pipe at 8%).
// Net persistent regs: 0 (w3u out, afr2 in). Grid/bounds per R14:
// (256,3) cap ~85 (measured 84, no spill), grid 1024 co-resident.

typedef __attribute__((ext_vector_type(2))) __fp16 h2;
typedef __attribute__((ext_vector_type(8))) __fp16 h8;
typedef __attribute__((ext_vector_type(4))) float f32x4;

#define NOUT   131072
#define NJOBS  (NOUT / 16)           // 8192 jobs of 16 outputs x 5 chains

// packed-half constants (both halves identical) -- halved validated quartic
#define C0H 0x3B913B91u  //  0.9458   (= 1.8916/2)
#define C1H 0xB996B996u  // -0.69824  (= -1.3965/2)
#define HALFC 0x38003800u//  0.5

__device__ __forceinline__ unsigned u_of(h2 x) { return __builtin_bit_cast(unsigned, x); }
__device__ __forceinline__ unsigned pkrtz_u(float a, float b) {
  return u_of(__builtin_amdgcn_cvt_pkrtz(a, b));
}
__device__ __forceinline__ unsigned pk_fma_vvv(unsigned a, unsigned b, unsigned c) {
  unsigned d; asm("v_pk_fma_f16 %0, %1, %2, %3" : "=v"(d) : "v"(a), "v"(b), "v"(c)); return d;
}
__device__ __forceinline__ unsigned pk_fma_vvs(unsigned a, unsigned b, unsigned cs) {
  unsigned d; asm("v_pk_fma_f16 %0, %1, %2, %3" : "=v"(d) : "v"(a), "v"(b), "s"(cs)); return d;
}
__device__ __forceinline__ unsigned pk_fma_clamp_vvs(unsigned a, unsigned b, unsigned cs) {
  unsigned d; asm("v_pk_fma_f16 %0, %1, %2, %3 clamp" : "=v"(d) : "v"(a), "v"(b), "s"(cs)); return d;
}
__device__ __forceinline__ unsigned pk_mul_vv(unsigned a, unsigned b) {
  unsigned d; asm("v_pk_mul_f16 %0, %1, %2" : "=v"(d) : "v"(a), "v"(b)); return d;
}
// 4-op half-sigmoid: q = clamp01(0.5 + s*(c0h + c1h*w + c2h*w^2)), w=s*s.
__device__ __forceinline__ unsigned tanh4(unsigned s, unsigned c2v) {
  unsigned w = pk_mul_vv(s, s);
  unsigned p = pk_fma_vvs(c2v, w, C1H);
  p = pk_fma_vvs(p, w, C0H);
  return pk_fma_clamp_vvs(s, p, HALFC);
}

union HU { unsigned u[4]; h8 v; };

__global__ __launch_bounds__(256, 3) void ode_mfma_kernel(
    const float* __restrict__ sigmap,  // [NPTS,3]
    const float* __restrict__ Wpp,     // [NPTS]
    const float* __restrict__ W1p,     // [2,64]
    const float* __restrict__ b1p,     // [64]
    const float* __restrict__ W2p,     // [64,64]
    const float* __restrict__ b2p,     // [64]
    const float* __restrict__ W3p,     // [64,1]
    const float* __restrict__ b3p,     // [1]
    float* __restrict__ outp)          // [131072]
{
  const int lane = threadIdx.x & 63;
  const int col  = lane & 15;   // output slot within job (B-col == D-col)
  const int g    = lane >> 4;   // lane group (k-group / D-row group)
  const int wid  = blockIdx.x * (blockDim.x >> 6) + (threadIdx.x >> 6);
  const int nw   = gridDim.x * (blockDim.x >> 6);

  // pinned VGPR for c2h = 0.20898 packed
  unsigned c2v; asm("v_mov_b32 %0, 0x32B032B0" : "=v"(c2v));

  // out-hidden j for (tile t, row i) -- R8-validated permutation
  auto j_of = [](int t, int i) {
    return 32 * (t >> 1) + 8 * (i >> 2) + 4 * (t & 1) + (i & 3);
  };

  // colsum[j] = sum_k W2[k][j], once per block (256B LDS)
  __shared__ float colsum[64];
  if (threadIdx.x < 64) {
    float s = 0.0f;
    for (int k = 0; k < 64; ++k) s += W2p[k * 64 + threadIdx.x];
    colsum[threadIdx.x] = s;
  }
  __syncthreads();

  // ---- persistent per-lane constants ----
  // layer1 packed pair ee: ee<4 -> j0=8g+2ee (k-frag 0); ee>=4 -> 32+8g+2(ee-4).
  unsigned w10u[8], w11u[8], b01u[8];
#pragma unroll
  for (int ee = 0; ee < 8; ++ee) {
    int j0 = (ee < 4) ? (8 * g + 2 * ee) : (32 + 8 * g + 2 * (ee - 4));
    w10u[ee] = pkrtz_u(0.5f * W1p[j0],      0.5f * W1p[j0 + 1]);
    w11u[ee] = pkrtz_u(0.5f * W1p[64 + j0], 0.5f * W1p[64 + j0 + 1]);
    b01u[ee] = pkrtz_u(0.5f * b1p[j0],      0.5f * b1p[j0 + 1]);
  }
  // layer2 A-frags: A[row=col][k] = W2[k][j_of(t,col)] RAW (sigmoid fold).
  HU afr[4][2];
#pragma unroll
  for (int t = 0; t < 4; ++t) {
    int jc = j_of(t, col);
#pragma unroll
    for (int kt = 0; kt < 2; ++kt)
#pragma unroll
      for (int ee = 0; ee < 4; ++ee) {
        int k0 = kt * 32 + 8 * g + 2 * ee;
        afr[t][kt].u[ee] = pkrtz_u(W2p[(k0)     * 64 + jc],
                                   W2p[(k0 + 1) * 64 + jc]);
      }
  }
  // layer2 C-init: lane reg r of tile t -> j_of(t,4g+r); 0.5*(b2 - colsum).
  f32x4 cinit[4];
#pragma unroll
  for (int t = 0; t < 4; ++t)
#pragma unroll
    for (int r = 0; r < 4; ++r) {
      int j = j_of(t, 4 * g + r);
      cinit[t][r] = 0.5f * (b2p[j] - colsum[j]);
    }
  // W3-MFMA A-frags (broadcast rows): A2[*][k] = 2*W3[k] (sigmoid fold).
  HU afr2[2];
#pragma unroll
  for (int kt = 0; kt < 2; ++kt)
#pragma unroll
    for (int ee = 0; ee < 4; ++ee) {
      int k0 = kt * 32 + 8 * g + 2 * ee;
      afr2[kt].u[ee] = pkrtz_u(2.0f * W3p[k0], 2.0f * W3p[k0 + 1]);
    }
  float sw3 = 0.0f;
  for (int k = 0; k < 64; ++k) sw3 += W3p[k];
  const float b3v = b3p[0] - sw3;   // y = 2*W3^T q2 + (b3 - sum W3)

#pragma unroll 1
  for (int job = wid; job < NJOBS; job += nw) {
    const int pbase = job * 80 + 5 * col;   // point p = pbase + s, s=0..4

    float x[5];
    unsigned uh[5];
#pragma unroll
    for (int s = 0; s < 5; ++s) {
      const int p = pbase + s;
      x[s]  = sigmap[3 * p + 0];
      float us = sigmap[3 * p + 1];
      uh[s] = pkrtz_u(us, us);
    }

    // 5-chain RHS, shuffle-free: y comes out of the W3-MFMA replicated.
    auto rhs5 = [&](const float* xi, float* o) {
#pragma unroll
      for (int s = 0; s < 5; ++s) {
        unsigned xh = pkrtz_u(xi[s], xi[s]);
        HU b0, b1;
#pragma unroll
        for (int ee = 0; ee < 4; ++ee) {
          unsigned cv0 = pk_fma_vvv(uh[s], w11u[ee],     b01u[ee]);
          unsigned cv1 = pk_fma_vvv(uh[s], w11u[ee + 4], b01u[ee + 4]);
          b0.u[ee] = tanh4(pk_fma_vvv(xh, w10u[ee],     cv0), c2v);
          b1.u[ee] = tanh4(pk_fma_vvv(xh, w10u[ee + 4], cv1), c2v);
        }
        // layer2: tile pair (2tp, 2tp+1) fills W3-B-frag q2f[tp]
        // (elem e = 4*(t&1)+r matches k-set of afr2[tp]).
        HU q2f[2];
#pragma unroll
        for (int tp = 0; tp < 2; ++tp) {
          f32x4 a0 = cinit[2 * tp], a1 = cinit[2 * tp + 1];
          a0 = __builtin_amdgcn_mfma_f32_16x16x32_f16(afr[2 * tp][0].v,     b0.v, a0, 0, 0, 0);
          a1 = __builtin_amdgcn_mfma_f32_16x16x32_f16(afr[2 * tp + 1][0].v, b0.v, a1, 0, 0, 0);
          a0 = __builtin_amdgcn_mfma_f32_16x16x32_f16(afr[2 * tp][1].v,     b1.v, a0, 0, 0, 0);
          a1 = __builtin_amdgcn_mfma_f32_16x16x32_f16(afr[2 * tp + 1][1].v, b1.v, a1, 0, 0, 0);
          q2f[tp].u[0] = tanh4(pkrtz_u(a0[0], a0[1]), c2v);
          q2f[tp].u[1] = tanh4(pkrtz_u(a0[2], a0[3]), c2v);
          q2f[tp].u[2] = tanh4(pkrtz_u(a1[0], a1[1]), c2v);
          q2f[tp].u[3] = tanh4(pkrtz_u(a1[2], a1[3]), c2v);
        }
        // layer3 on matrix pipe: D = 2*W3^T q2 + b3v, replicated all lanes.
        f32x4 y = {b3v, b3v, b3v, b3v};
        y = __builtin_amdgcn_mfma_f32_16x16x32_f16(afr2[0].v, q2f[0].v, y, 0, 0, 0);
        y = __builtin_amdgcn_mfma_f32_16x16x32_f16(afr2[1].v, q2f[1].v, y, 0, 0, 0);
        o[s] = y[0];
      }
    };

    // midpoint: x_end = x0 + DT * f(x0 + DT/2 * f(x0)); then diffusion kick.
    float k1[5], k2[5];
    rhs5(x, k1);
#pragma unroll
    for (int s = 0; s < 5; ++s) k1[s] = fmaf(0.005f, k1[s], x[s]);  // xm in-place
    rhs5(k1, k2);

    // final combine: wd/wq loaded here (L2-hit) instead of held in regs.
    float y = 0.0f;
#pragma unroll
    for (int s = 0; s < 5; ++s) {
      const int p = pbase + s;
      float xe = fmaf(0.01f, k2[s], x[s]);
      xe = fmaf(0.01f, sigmap[3 * p + 2], xe);  // sqrt(2*0.5*sigma^2*dt)=0.01
      y = fmaf(Wpp[p], xe, y);
    }

    if (lane < 16) outp[job * 16 + col] = y;   // plain store, no atomics
  }
}

extern "C" void kernel_launch(void* const* d_in, const int* in_sizes, int n_in,
                              void* d_out, int out_size, void* d_ws, size_t ws_size,
                              hipStream_t stream) {
  const float* sigmap = (const float*)d_in[0];
  const float* Wpp    = (const float*)d_in[1];
  const float* W1p    = (const float*)d_in[2];
  const float* b1p    = (const float*)d_in[3];
  const float* W2p    = (const float*)d_in[4];
  const float* b2p    = (const float*)d_in[5];
  const float* W3p    = (const float*)d_in[6];
  const float* b3p    = (const float*)d_in[7];
  float* outp = (float*)d_out;

  // 1024 blocks = 4/CU, fully co-resident; 4096 waves x exactly 2 jobs.
  ode_mfma_kernel<<<1024, 256, 0, stream>>>(sigmap, Wpp, W1p, b1p, W2p, b2p,
                                            W3p, b3p, outp);
  (void)d_ws; (void)ws_size; (void)n_in; (void)in_sizes;
}